// Round 1
// baseline (296.105 us; speedup 1.0000x reference)
//
#include <hip/hip_runtime.h>

typedef __bf16 bf16x8 __attribute__((ext_vector_type(8)));
typedef float f32x4 __attribute__((ext_vector_type(4)));

#define S_LEN 2048
#define D_DIM 64

__global__ __launch_bounds__(256) void attn_fwd(const float* __restrict__ Q,
                                                const float* __restrict__ K,
                                                const float* __restrict__ V,
                                                float* __restrict__ O) {
    // grid: x = q-block (S/64 = 32), y = head (B*H = 32)
    const int head = blockIdx.y;
    const int qblk = blockIdx.x;
    const int tid  = threadIdx.x;
    const int wave = tid >> 6;
    const int lane = tid & 63;
    const int l15  = lane & 15;
    const int lhi  = lane >> 4;              // 0..3

    const int q0 = qblk * 64 + wave * 16;    // first query row owned by this wave
    const size_t base = (size_t)head * (S_LEN * D_DIM);

    // D^-0.5 * log2(e): softmax done in exp2 domain
    const float qscale = 0.125f * 1.44269504088896340736f;

    __shared__ __align__(16) __bf16 p_lds_all[4][16][32];
    __bf16 (*p_lds)[32] = p_lds_all[wave];

    // ---- Q fragments (A-frag: row = l15, k = lhi*8+e), two 32-wide k-halves ----
    bf16x8 qf[2];
    {
        const float* qrow = Q + base + (size_t)(q0 + l15) * D_DIM + lhi * 8;
        #pragma unroll
        for (int h = 0; h < 2; ++h) {
            const float4 a = *(const float4*)(qrow + h * 32);
            const float4 b = *(const float4*)(qrow + h * 32 + 4);
            qf[h][0] = (__bf16)(a.x * qscale); qf[h][1] = (__bf16)(a.y * qscale);
            qf[h][2] = (__bf16)(a.z * qscale); qf[h][3] = (__bf16)(a.w * qscale);
            qf[h][4] = (__bf16)(b.x * qscale); qf[h][5] = (__bf16)(b.y * qscale);
            qf[h][6] = (__bf16)(b.z * qscale); qf[h][7] = (__bf16)(b.w * qscale);
        }
    }

    f32x4 acc[4];
    #pragma unroll
    for (int t = 0; t < 4; ++t) acc[t] = (f32x4){0.f, 0.f, 0.f, 0.f};
    float m_r[4], l_r[4];
    #pragma unroll
    for (int r = 0; r < 4; ++r) { m_r[r] = -1e30f; l_r[r] = 0.f; }

    const int ntiles = (q0 + 47) >> 5;       // KV tiles of 32 covering keys [0, q0+16)
    for (int kt = 0; kt < ntiles; ++kt) {
        const int kv0 = kt << 5;

        // ---- S = Q K^T  (two 16-col tiles, two k-halves each) ----
        f32x4 s[2];
        s[0] = (f32x4){0.f, 0.f, 0.f, 0.f};
        s[1] = (f32x4){0.f, 0.f, 0.f, 0.f};
        #pragma unroll
        for (int t = 0; t < 2; ++t) {
            const float* krow = K + base + (size_t)(kv0 + t * 16 + l15) * D_DIM + lhi * 8;
            #pragma unroll
            for (int h = 0; h < 2; ++h) {
                const float4 a = *(const float4*)(krow + h * 32);
                const float4 b = *(const float4*)(krow + h * 32 + 4);
                bf16x8 kf;
                kf[0] = (__bf16)a.x; kf[1] = (__bf16)a.y; kf[2] = (__bf16)a.z; kf[3] = (__bf16)a.w;
                kf[4] = (__bf16)b.x; kf[5] = (__bf16)b.y; kf[6] = (__bf16)b.z; kf[7] = (__bf16)b.w;
                s[t] = __builtin_amdgcn_mfma_f32_16x16x32_bf16(qf[h], kf, s[t], 0, 0, 0);
            }
        }

        // ---- causal mask (only boundary tiles need it) ----
        if (kv0 + 31 > q0) {
            #pragma unroll
            for (int t = 0; t < 2; ++t)
                #pragma unroll
                for (int r = 0; r < 4; ++r) {
                    const int kg = kv0 + t * 16 + l15;
                    const int qg = q0 + lhi * 4 + r;
                    if (kg > qg) s[t][r] = -1e30f;
                }
        }

        // ---- online softmax (rows live in 16-lane groups) ----
        float f[4];
        #pragma unroll
        for (int r = 0; r < 4; ++r) {
            float mm = fmaxf(s[0][r], s[1][r]);
            mm = fmaxf(mm, __shfl_xor(mm, 1));
            mm = fmaxf(mm, __shfl_xor(mm, 2));
            mm = fmaxf(mm, __shfl_xor(mm, 4));
            mm = fmaxf(mm, __shfl_xor(mm, 8));
            const float mn = fmaxf(m_r[r], mm);
            f[r] = exp2f(m_r[r] - mn);
            m_r[r] = mn;
            const float p0 = exp2f(s[0][r] - mn);
            const float p1 = exp2f(s[1][r] - mn);
            s[0][r] = p0; s[1][r] = p1;
            float ps = p0 + p1;
            ps += __shfl_xor(ps, 1);
            ps += __shfl_xor(ps, 2);
            ps += __shfl_xor(ps, 4);
            ps += __shfl_xor(ps, 8);
            l_r[r] = l_r[r] * f[r] + ps;
        }

        // ---- P (C/D layout) -> LDS -> A-frag layout ----
        #pragma unroll
        for (int t = 0; t < 2; ++t)
            #pragma unroll
            for (int r = 0; r < 4; ++r)
                p_lds[lhi * 4 + r][t * 16 + l15] = (__bf16)s[t][r];
        asm volatile("s_waitcnt lgkmcnt(0)" ::: "memory");
        const bf16x8 pf = *(const bf16x8*)&p_lds[l15][lhi * 8];
        asm volatile("" ::: "memory");   // keep next iter's LDS writes below this read

        // ---- rescale accumulators ----
        #pragma unroll
        for (int t = 0; t < 4; ++t)
            #pragma unroll
            for (int r = 0; r < 4; ++r)
                acc[t][r] *= f[r];

        // ---- O += P V  (B-frag of V: col = d = td*16+l15, k = key = lhi*8+e) ----
        #pragma unroll
        for (int td = 0; td < 4; ++td) {
            const float* vcol = V + base + (size_t)(kv0 + lhi * 8) * D_DIM + td * 16 + l15;
            bf16x8 vf;
            #pragma unroll
            for (int e = 0; e < 8; ++e) vf[e] = (__bf16)vcol[e * D_DIM];
            acc[td] = __builtin_amdgcn_mfma_f32_16x16x32_bf16(pf, vf, acc[td], 0, 0, 0);
        }
    }

    // ---- epilogue: O = acc / l ----
    float* orow = O + base + (size_t)q0 * D_DIM;
    #pragma unroll
    for (int td = 0; td < 4; ++td) {
        #pragma unroll
        for (int r = 0; r < 4; ++r) {
            const float inv = 1.0f / l_r[r];
            orow[(size_t)(lhi * 4 + r) * D_DIM + td * 16 + l15] = acc[td][r] * inv;
        }
    }
}

extern "C" void kernel_launch(void* const* d_in, const int* in_sizes, int n_in,
                              void* d_out, int out_size, void* d_ws, size_t ws_size,
                              hipStream_t stream) {
    const float* q = (const float*)d_in[0];
    const float* k = (const float*)d_in[1];
    const float* v = (const float*)d_in[2];
    float* o = (float*)d_out;
    dim3 grid(S_LEN / 64, 32);   // 32 q-blocks x (B*H = 32) heads
    attn_fwd<<<grid, dim3(256), 0, stream>>>(q, k, v, o);
}

// Round 2
// 139.212 us; speedup vs baseline: 2.1270x; 2.1270x over previous
//
#include <hip/hip_runtime.h>

typedef __bf16 bf16x8 __attribute__((ext_vector_type(8)));
typedef float f32x4 __attribute__((ext_vector_type(4)));

#define S_LEN 2048
#define D_DIM 64

__device__ inline bf16x8 cvt8(float4 a, float4 b) {
    bf16x8 t;
    t[0] = (__bf16)a.x; t[1] = (__bf16)a.y; t[2] = (__bf16)a.z; t[3] = (__bf16)a.w;
    t[4] = (__bf16)b.x; t[5] = (__bf16)b.y; t[6] = (__bf16)b.z; t[7] = (__bf16)b.w;
    return t;
}

__global__ __launch_bounds__(256) void attn_fwd(const float* __restrict__ Q,
                                                const float* __restrict__ K,
                                                const float* __restrict__ V,
                                                float* __restrict__ O) {
    // XCD-aware bijective swizzle: 512 blocks, 8 XCDs, 64 blocks/XCD chunk.
    const int orig = blockIdx.x + (blockIdx.y << 4);
    const int sid  = ((orig & 7) << 6) + (orig >> 3);
    const int qblk = sid & 15;          // 16 q-blocks of 128 rows
    const int head = sid >> 4;          // 32 heads

    const int tid  = threadIdx.x;
    const int wave = tid >> 6;
    const int lane = tid & 63;
    const int l15  = lane & 15;
    const int lhi  = lane >> 4;

    const int q0 = qblk * 128 + wave * 32;          // wave owns rows q0..q0+31
    const size_t base = (size_t)head * (S_LEN * D_DIM);
    const float qscale = 0.125f * 1.44269504088896340736f;   // D^-0.5 * log2(e)

    __shared__ __align__(16) __bf16 Klds[64][64];      // [key][d], col ^ ((key&7)<<3)
    __shared__ __align__(16) __bf16 Vt[64][64];        // [d][key], col ^ (d&56)
    __shared__ __align__(16) __bf16 Plds[4][32][64];   // per wave [q][key], col ^ ((q&7)<<3)

    // staging coords: 256 threads cover 32 rows x 64 cols per unit, 2 units
    const int sr = tid >> 3;            // 0..31
    const int sc = (tid & 7) << 3;      // 0,8,...,56

    // ---- Q fragments (A-frag: row=l15, k=lhi*8+e), 2 row-tiles x 2 k-halves ----
    bf16x8 qf[2][2];
    #pragma unroll
    for (int rt = 0; rt < 2; ++rt) {
        const float* qrow = Q + base + (size_t)(q0 + rt * 16 + l15) * D_DIM + lhi * 8;
        #pragma unroll
        for (int h = 0; h < 2; ++h) {
            float4 a = *(const float4*)(qrow + h * 32);
            float4 b = *(const float4*)(qrow + h * 32 + 4);
            bf16x8 t;
            t[0] = (__bf16)(a.x * qscale); t[1] = (__bf16)(a.y * qscale);
            t[2] = (__bf16)(a.z * qscale); t[3] = (__bf16)(a.w * qscale);
            t[4] = (__bf16)(b.x * qscale); t[5] = (__bf16)(b.y * qscale);
            t[6] = (__bf16)(b.z * qscale); t[7] = (__bf16)(b.w * qscale);
            qf[rt][h] = t;
        }
    }

    f32x4 acc[2][4];
    #pragma unroll
    for (int rt = 0; rt < 2; ++rt)
        #pragma unroll
        for (int td = 0; td < 4; ++td) acc[rt][td] = (f32x4){0.f, 0.f, 0.f, 0.f};
    float m_r[2][4], l_r[2][4];
    #pragma unroll
    for (int rt = 0; rt < 2; ++rt)
        #pragma unroll
        for (int r = 0; r < 4; ++r) { m_r[rt][r] = -1e30f; l_r[rt][r] = 0.f; }

    const int ntiles = 2 * qblk + 2;    // KV-64 tiles covering keys <= qblk*128+127
    for (int kt = 0; kt < ntiles; ++kt) {
        const int kv0 = kt << 6;

        __syncthreads();                // previous tile's LDS reads done
        // ---- stage K (swizzled row-major) and V (swizzled transposed) ----
        #pragma unroll
        for (int u = 0; u < 2; ++u) {
            const int r = sr + u * 32;
            const float* ks = K + base + (size_t)(kv0 + r) * D_DIM + sc;
            const float* vs = V + base + (size_t)(kv0 + r) * D_DIM + sc;
            float4 ka = *(const float4*)ks, kb = *(const float4*)(ks + 4);
            float4 va = *(const float4*)vs, vb = *(const float4*)(vs + 4);
            *(bf16x8*)&Klds[r][sc ^ ((r & 7) << 3)] = cvt8(ka, kb);
            const int vcol = r ^ sc;    // k ^ ((d&56)) with d-chunk = sc
            Vt[sc + 0][vcol] = (__bf16)va.x; Vt[sc + 1][vcol] = (__bf16)va.y;
            Vt[sc + 2][vcol] = (__bf16)va.z; Vt[sc + 3][vcol] = (__bf16)va.w;
            Vt[sc + 4][vcol] = (__bf16)vb.x; Vt[sc + 5][vcol] = (__bf16)vb.y;
            Vt[sc + 6][vcol] = (__bf16)vb.z; Vt[sc + 7][vcol] = (__bf16)vb.w;
        }
        __syncthreads();                // tile staged

        if (kv0 > q0 + 31) continue;    // fully masked for this wave

        // ---- S = Q K^T : 2 row-tiles x 4 col-tiles ----
        f32x4 s[2][4];
        #pragma unroll
        for (int rt = 0; rt < 2; ++rt)
            #pragma unroll
            for (int ct = 0; ct < 4; ++ct) s[rt][ct] = (f32x4){0.f, 0.f, 0.f, 0.f};
        #pragma unroll
        for (int h = 0; h < 2; ++h) {
            #pragma unroll
            for (int ct = 0; ct < 4; ++ct) {
                const int krow = ct * 16 + l15;
                bf16x8 kf = *(const bf16x8*)&Klds[krow][(h * 32 + lhi * 8) ^ ((l15 & 7) << 3)];
                s[0][ct] = __builtin_amdgcn_mfma_f32_16x16x32_bf16(qf[0][h], kf, s[0][ct], 0, 0, 0);
                s[1][ct] = __builtin_amdgcn_mfma_f32_16x16x32_bf16(qf[1][h], kf, s[1][ct], 0, 0, 0);
            }
        }

        // ---- causal mask (boundary tiles only) ----
        if (kv0 + 63 > q0) {
            #pragma unroll
            for (int rt = 0; rt < 2; ++rt)
                #pragma unroll
                for (int ct = 0; ct < 4; ++ct)
                    #pragma unroll
                    for (int r = 0; r < 4; ++r) {
                        const int kg = kv0 + ct * 16 + l15;
                        const int qg = q0 + rt * 16 + lhi * 4 + r;
                        if (kg > qg) s[rt][ct][r] = -1e30f;
                    }
        }

        // ---- online softmax over 8 rows ----
        float fscale[2][4];
        #pragma unroll
        for (int rt = 0; rt < 2; ++rt)
            #pragma unroll
            for (int r = 0; r < 4; ++r) {
                float mm = fmaxf(fmaxf(s[rt][0][r], s[rt][1][r]), fmaxf(s[rt][2][r], s[rt][3][r]));
                mm = fmaxf(mm, __shfl_xor(mm, 1));
                mm = fmaxf(mm, __shfl_xor(mm, 2));
                mm = fmaxf(mm, __shfl_xor(mm, 4));
                mm = fmaxf(mm, __shfl_xor(mm, 8));
                const float mn = fmaxf(m_r[rt][r], mm);
                const float f = exp2f(m_r[rt][r] - mn);
                m_r[rt][r] = mn;
                fscale[rt][r] = f;
                float p0 = exp2f(s[rt][0][r] - mn);
                float p1 = exp2f(s[rt][1][r] - mn);
                float p2 = exp2f(s[rt][2][r] - mn);
                float p3 = exp2f(s[rt][3][r] - mn);
                s[rt][0][r] = p0; s[rt][1][r] = p1; s[rt][2][r] = p2; s[rt][3][r] = p3;
                float ps = (p0 + p1) + (p2 + p3);
                ps += __shfl_xor(ps, 1);
                ps += __shfl_xor(ps, 2);
                ps += __shfl_xor(ps, 4);
                ps += __shfl_xor(ps, 8);
                l_r[rt][r] = l_r[rt][r] * f + ps;
            }

        // ---- P (C/D layout) -> per-wave LDS (swizzled) -> A-frags ----
        #pragma unroll
        for (int rt = 0; rt < 2; ++rt)
            #pragma unroll
            for (int ct = 0; ct < 4; ++ct)
                #pragma unroll
                for (int r = 0; r < 4; ++r) {
                    const int prow = rt * 16 + lhi * 4 + r;
                    Plds[wave][prow][(ct * 16 + l15) ^ ((prow & 7) << 3)] = (__bf16)s[rt][ct][r];
                }
        asm volatile("s_waitcnt lgkmcnt(0)" ::: "memory");
        bf16x8 pf[2][2];
        #pragma unroll
        for (int rt = 0; rt < 2; ++rt)
            #pragma unroll
            for (int kh = 0; kh < 2; ++kh)
                pf[rt][kh] = *(const bf16x8*)&Plds[wave][rt * 16 + l15][(kh * 32 + lhi * 8) ^ ((l15 & 7) << 3)];
        asm volatile("" ::: "memory");

        // ---- rescale accumulators ----
        #pragma unroll
        for (int rt = 0; rt < 2; ++rt)
            #pragma unroll
            for (int td = 0; td < 4; ++td)
                #pragma unroll
                for (int r = 0; r < 4; ++r)
                    acc[rt][td][r] *= fscale[rt][r];

        // ---- O += P V ----
        #pragma unroll
        for (int kh = 0; kh < 2; ++kh) {
            #pragma unroll
            for (int td = 0; td < 4; ++td) {
                const int vrow = td * 16 + l15;
                bf16x8 vf = *(const bf16x8*)&Vt[vrow][(kh * 32 + lhi * 8) ^ (vrow & 56)];
                acc[0][td] = __builtin_amdgcn_mfma_f32_16x16x32_bf16(pf[0][kh], vf, acc[0][td], 0, 0, 0);
                acc[1][td] = __builtin_amdgcn_mfma_f32_16x16x32_bf16(pf[1][kh], vf, acc[1][td], 0, 0, 0);
            }
        }
    }

    // ---- epilogue ----
    float invl[2][4];
    #pragma unroll
    for (int rt = 0; rt < 2; ++rt)
        #pragma unroll
        for (int r = 0; r < 4; ++r) invl[rt][r] = 1.0f / l_r[rt][r];
    float* orow = O + base + (size_t)q0 * D_DIM;
    #pragma unroll
    for (int rt = 0; rt < 2; ++rt)
        #pragma unroll
        for (int td = 0; td < 4; ++td)
            #pragma unroll
            for (int r = 0; r < 4; ++r)
                orow[(size_t)(rt * 16 + lhi * 4 + r) * D_DIM + td * 16 + l15] = acc[rt][td][r] * invl[rt][r];
}

extern "C" void kernel_launch(void* const* d_in, const int* in_sizes, int n_in,
                              void* d_out, int out_size, void* d_ws, size_t ws_size,
                              hipStream_t stream) {
    const float* q = (const float*)d_in[0];
    const float* k = (const float*)d_in[1];
    const float* v = (const float*)d_in[2];
    float* o = (float*)d_out;
    dim3 grid(16, 32);   // 16 q-blocks x (B*H = 32) heads, swizzled in-kernel
    attn_fwd<<<grid, dim3(256), 0, stream>>>(q, k, v, o);
}

// Round 3
// 110.717 us; speedup vs baseline: 2.6744x; 1.2574x over previous
//
#include <hip/hip_runtime.h>

typedef __bf16 bf16x8 __attribute__((ext_vector_type(8)));
typedef float f32x4 __attribute__((ext_vector_type(4)));

#define S_LEN 2048
#define D_DIM 64

__global__ __launch_bounds__(256) void attn_fwd(const float* __restrict__ Q,
                                                const float* __restrict__ K,
                                                const float* __restrict__ V,
                                                float* __restrict__ O) {
    // Deterministic CU-pairing + XCD-locality mapping.
    // Assumes HW places block b on XCD b%8, CU-slot (b/8)%32, wave j=b/256.
    // Blocks sharing a CU get chunks (slot, 15-slot) of the same head ->
    // per-CU work = 34 KV-tiles, uniform. Bijective -> correct regardless.
    const int b     = blockIdx.x;
    const int xcd   = b & 7;
    const int c     = (b >> 3) & 31;
    const int j     = b >> 8;                 // 0 or 1
    const int head  = xcd * 4 + (c >> 3);     // 4 heads per XCD
    const int slot  = c & 7;
    const int chunk = j ? (15 - slot) : slot; // 128-row q-chunk, 0..15

    const int tid  = threadIdx.x;
    const int wave = tid >> 6;
    const int lane = tid & 63;
    const int l15  = lane & 15;
    const int lhi  = lane >> 4;

    const int q0 = chunk * 128 + wave * 32;   // wave owns rows q0..q0+31
    const size_t base = (size_t)head * (S_LEN * D_DIM);
    const float qscale = 0.125f * 1.44269504088896340736f;  // D^-0.5 * log2(e)

    __shared__ __align__(16) __bf16 Klds[2][64][64];   // [buf][key][d], col ^ ((key&7)<<3)
    __shared__ __align__(16) __bf16 Vt[2][64][64];     // [buf][d][key], col ^ ((d&7)<<3)
    __shared__ __align__(16) __bf16 Plds[4][32][64];   // per wave [q][key], col ^ ((q&7)<<3)

    // staging coords
    const int rk = tid >> 2;            // K row 0..63
    const int ck = (tid & 3) << 4;      // K col 0,16,32,48
    const int kp = tid & 31;            // V key-pair (keys 2kp, 2kp+1)
    const int dc = tid >> 5;            // V d-chunk 0..7 (8 d each)
    const int swk = (rk & 7) << 3;

    // ---- Q fragments (A-frag: row=l15, k=lhi*8+e), 2 row-tiles x 2 k-halves ----
    bf16x8 qf[2][2];
    #pragma unroll
    for (int rt = 0; rt < 2; ++rt) {
        const float* qrow = Q + base + (size_t)(q0 + rt * 16 + l15) * D_DIM + lhi * 8;
        #pragma unroll
        for (int h = 0; h < 2; ++h) {
            f32x4 a = *(const f32x4*)(qrow + h * 32);
            f32x4 bq = *(const f32x4*)(qrow + h * 32 + 4);
            bf16x8 t;
            #pragma unroll
            for (int e = 0; e < 4; ++e) { t[e] = (__bf16)(a[e] * qscale); t[e + 4] = (__bf16)(bq[e] * qscale); }
            qf[rt][h] = t;
        }
    }

    f32x4 acc[2][4];
    #pragma unroll
    for (int rt = 0; rt < 2; ++rt)
        #pragma unroll
        for (int td = 0; td < 4; ++td) acc[rt][td] = (f32x4){0.f, 0.f, 0.f, 0.f};
    float m_r[2][4], l_r[2][4];
    #pragma unroll
    for (int rt = 0; rt < 2; ++rt)
        #pragma unroll
        for (int r = 0; r < 4; ++r) { m_r[rt][r] = -1e30f; l_r[rt][r] = 0.f; }

    f32x4 pk[4], pva[2], pvb[2];

    // ---- prologue: stage tile 0 into buf 0 ----
    {
        const float* ks = K + base + (size_t)rk * D_DIM + ck;
        #pragma unroll
        for (int i = 0; i < 4; ++i) pk[i] = *(const f32x4*)(ks + 4 * i);
        const float* v0 = V + base + (size_t)(2 * kp) * D_DIM + dc * 8;
        pva[0] = *(const f32x4*)v0;           pva[1] = *(const f32x4*)(v0 + 4);
        pvb[0] = *(const f32x4*)(v0 + D_DIM); pvb[1] = *(const f32x4*)(v0 + D_DIM + 4);
        bf16x8 k0, k1;
        #pragma unroll
        for (int e = 0; e < 4; ++e) {
            k0[e] = (__bf16)pk[0][e]; k0[e + 4] = (__bf16)pk[1][e];
            k1[e] = (__bf16)pk[2][e]; k1[e + 4] = (__bf16)pk[3][e];
        }
        *(bf16x8*)&Klds[0][rk][ck ^ swk] = k0;
        *(bf16x8*)&Klds[0][rk][(ck + 8) ^ swk] = k1;
        #pragma unroll
        for (int jj = 0; jj < 8; ++jj) {
            const int d = dc * 8 + jj;
            const float av = (jj < 4) ? pva[0][jj & 3] : pva[1][jj & 3];
            const float bv = (jj < 4) ? pvb[0][jj & 3] : pvb[1][jj & 3];
            union { __bf16 h[2]; unsigned int u; } t;
            t.h[0] = (__bf16)av; t.h[1] = (__bf16)bv;
            *(unsigned int*)&Vt[0][d][(2 * kp) ^ ((d & 7) << 3)] = t.u;
        }
    }

    const int nt = 2 * chunk + 2;
    for (int kt = 0; kt < nt; ++kt) {
        const int cur = kt & 1;
        __syncthreads();                 // buf[cur] staged; prev reads of buf[cur^1] done

        const bool pre = (kt + 1 < nt);
        if (pre) {                        // issue next-tile loads (latency hides under compute)
            const int kv1 = (kt + 1) << 6;
            const float* ks = K + base + (size_t)(kv1 + rk) * D_DIM + ck;
            #pragma unroll
            for (int i = 0; i < 4; ++i) pk[i] = *(const f32x4*)(ks + 4 * i);
            const float* v0 = V + base + (size_t)(kv1 + 2 * kp) * D_DIM + dc * 8;
            pva[0] = *(const f32x4*)v0;           pva[1] = *(const f32x4*)(v0 + 4);
            pvb[0] = *(const f32x4*)(v0 + D_DIM); pvb[1] = *(const f32x4*)(v0 + D_DIM + 4);
        }

        const int kv0 = kt << 6;
        if (kv0 <= q0 + 31) {            // not fully masked for this wave
            // ---- S = Q K^T ----
            f32x4 s[2][4];
            #pragma unroll
            for (int rt = 0; rt < 2; ++rt)
                #pragma unroll
                for (int ct = 0; ct < 4; ++ct) s[rt][ct] = (f32x4){0.f, 0.f, 0.f, 0.f};
            __builtin_amdgcn_s_setprio(1);
            #pragma unroll
            for (int h = 0; h < 2; ++h) {
                #pragma unroll
                for (int ct = 0; ct < 4; ++ct) {
                    const int krow = ct * 16 + l15;
                    bf16x8 kf = *(const bf16x8*)&Klds[cur][krow][(h * 32 + lhi * 8) ^ ((l15 & 7) << 3)];
                    s[0][ct] = __builtin_amdgcn_mfma_f32_16x16x32_bf16(qf[0][h], kf, s[0][ct], 0, 0, 0);
                    s[1][ct] = __builtin_amdgcn_mfma_f32_16x16x32_bf16(qf[1][h], kf, s[1][ct], 0, 0, 0);
                }
            }
            __builtin_amdgcn_s_setprio(0);

            // ---- causal mask (boundary tiles only) ----
            if (kv0 + 63 > q0) {
                #pragma unroll
                for (int rt = 0; rt < 2; ++rt)
                    #pragma unroll
                    for (int ct = 0; ct < 4; ++ct)
                        #pragma unroll
                        for (int r = 0; r < 4; ++r) {
                            const int kg = kv0 + ct * 16 + l15;
                            const int qg = q0 + rt * 16 + lhi * 4 + r;
                            if (kg > qg) s[rt][ct][r] = -1e30f;
                        }
            }

            // ---- online softmax ----
            float fscale[2][4];
            #pragma unroll
            for (int rt = 0; rt < 2; ++rt)
                #pragma unroll
                for (int r = 0; r < 4; ++r) {
                    float mm = fmaxf(fmaxf(s[rt][0][r], s[rt][1][r]), fmaxf(s[rt][2][r], s[rt][3][r]));
                    mm = fmaxf(mm, __shfl_xor(mm, 1));
                    mm = fmaxf(mm, __shfl_xor(mm, 2));
                    mm = fmaxf(mm, __shfl_xor(mm, 4));
                    mm = fmaxf(mm, __shfl_xor(mm, 8));
                    const float mn = fmaxf(m_r[rt][r], mm);
                    const float f = exp2f(m_r[rt][r] - mn);
                    m_r[rt][r] = mn;
                    fscale[rt][r] = f;
                    float p0 = exp2f(s[rt][0][r] - mn);
                    float p1 = exp2f(s[rt][1][r] - mn);
                    float p2 = exp2f(s[rt][2][r] - mn);
                    float p3 = exp2f(s[rt][3][r] - mn);
                    s[rt][0][r] = p0; s[rt][1][r] = p1; s[rt][2][r] = p2; s[rt][3][r] = p3;
                    float ps = (p0 + p1) + (p2 + p3);
                    ps += __shfl_xor(ps, 1);
                    ps += __shfl_xor(ps, 2);
                    ps += __shfl_xor(ps, 4);
                    ps += __shfl_xor(ps, 8);
                    l_r[rt][r] = l_r[rt][r] * f + ps;
                }

            // ---- P (C/D layout) -> per-wave LDS (swizzled) -> A-frags ----
            #pragma unroll
            for (int rt = 0; rt < 2; ++rt)
                #pragma unroll
                for (int ct = 0; ct < 4; ++ct)
                    #pragma unroll
                    for (int r = 0; r < 4; ++r) {
                        const int prow = rt * 16 + lhi * 4 + r;
                        Plds[wave][prow][(ct * 16 + l15) ^ ((prow & 7) << 3)] = (__bf16)s[rt][ct][r];
                    }
            asm volatile("s_waitcnt lgkmcnt(0)" ::: "memory");
            bf16x8 pf[2][2];
            #pragma unroll
            for (int rt = 0; rt < 2; ++rt)
                #pragma unroll
                for (int kh = 0; kh < 2; ++kh)
                    pf[rt][kh] = *(const bf16x8*)&Plds[wave][rt * 16 + l15][(kh * 32 + lhi * 8) ^ ((l15 & 7) << 3)];
            asm volatile("" ::: "memory");

            // ---- rescale + O += P V ----
            #pragma unroll
            for (int rt = 0; rt < 2; ++rt)
                #pragma unroll
                for (int td = 0; td < 4; ++td)
                    #pragma unroll
                    for (int r = 0; r < 4; ++r)
                        acc[rt][td][r] *= fscale[rt][r];
            __builtin_amdgcn_s_setprio(1);
            #pragma unroll
            for (int kh = 0; kh < 2; ++kh) {
                #pragma unroll
                for (int td = 0; td < 4; ++td) {
                    const int vrow = td * 16 + l15;
                    bf16x8 vf = *(const bf16x8*)&Vt[cur][vrow][(kh * 32 + lhi * 8) ^ ((vrow & 7) << 3)];
                    acc[0][td] = __builtin_amdgcn_mfma_f32_16x16x32_bf16(pf[0][kh], vf, acc[0][td], 0, 0, 0);
                    acc[1][td] = __builtin_amdgcn_mfma_f32_16x16x32_bf16(pf[1][kh], vf, acc[1][td], 0, 0, 0);
                }
            }
            __builtin_amdgcn_s_setprio(0);
        }

        if (pre) {                        // cvt + write into idle buffer (no barrier needed)
            const int nxt = cur ^ 1;
            bf16x8 k0, k1;
            #pragma unroll
            for (int e = 0; e < 4; ++e) {
                k0[e] = (__bf16)pk[0][e]; k0[e + 4] = (__bf16)pk[1][e];
                k1[e] = (__bf16)pk[2][e]; k1[e + 4] = (__bf16)pk[3][e];
            }
            *(bf16x8*)&Klds[nxt][rk][ck ^ swk] = k0;
            *(bf16x8*)&Klds[nxt][rk][(ck + 8) ^ swk] = k1;
            #pragma unroll
            for (int jj = 0; jj < 8; ++jj) {
                const int d = dc * 8 + jj;
                const float av = (jj < 4) ? pva[0][jj & 3] : pva[1][jj & 3];
                const float bv = (jj < 4) ? pvb[0][jj & 3] : pvb[1][jj & 3];
                union { __bf16 h[2]; unsigned int u; } t;
                t.h[0] = (__bf16)av; t.h[1] = (__bf16)bv;
                *(unsigned int*)&Vt[nxt][d][(2 * kp) ^ ((d & 7) << 3)] = t.u;
            }
        }
    }

    // ---- epilogue ----
    float* orow = O + base + (size_t)q0 * D_DIM;
    #pragma unroll
    for (int rt = 0; rt < 2; ++rt)
        #pragma unroll
        for (int r = 0; r < 4; ++r) {
            const float inv = 1.0f / l_r[rt][r];
            #pragma unroll
            for (int td = 0; td < 4; ++td)
                orow[(size_t)(rt * 16 + lhi * 4 + r) * D_DIM + td * 16 + l15] = acc[rt][td][r] * inv;
        }
}

extern "C" void kernel_launch(void* const* d_in, const int* in_sizes, int n_in,
                              void* d_out, int out_size, void* d_ws, size_t ws_size,
                              hipStream_t stream) {
    const float* q = (const float*)d_in[0];
    const float* k = (const float*)d_in[1];
    const float* v = (const float*)d_in[2];
    float* o = (float*)d_out;
    attn_fwd<<<dim3(512), dim3(256), 0, stream>>>(q, k, v, o);
}

// Round 4
// 89.869 us; speedup vs baseline: 3.2949x; 1.2320x over previous
//
#include <hip/hip_runtime.h>

typedef __bf16 bf16x8 __attribute__((ext_vector_type(8)));
typedef float f32x4 __attribute__((ext_vector_type(4)));

#define S_LEN 2048
#define D_DIM 64

__global__ __launch_bounds__(256, 4) void attn_fwd(const float* __restrict__ Q,
                                                   const float* __restrict__ K,
                                                   const float* __restrict__ V,
                                                   float* __restrict__ O) {
    // Deterministic CU-pairing + XCD-locality mapping (1024 blocks, 4/CU).
    // Assumes HW round-robin: block b -> XCD b%8, CU-slot (b/8)%32, pass j=b/256.
    // The 4 blocks sharing a CU get chunks {slot, 31-slot, slot+8, 23-slot} of one
    // head -> per-CU work = 66 KV-tiles, uniform. Bijective -> correct regardless.
    const int b    = blockIdx.x;
    const int xcd  = b & 7;
    const int cs   = (b >> 3) & 31;
    const int j    = b >> 8;                  // 0..3
    const int head = xcd * 4 + (cs >> 3);     // 4 heads per XCD
    const int slot = cs & 7;
    const int chunk = (j == 0) ? slot : (j == 1) ? (31 - slot)
                    : (j == 2) ? (slot + 8) : (23 - slot);   // 64-row q-chunk, 0..31

    const int tid  = threadIdx.x;
    const int wave = tid >> 6;
    const int lane = tid & 63;
    const int l15  = lane & 15;
    const int lhi  = lane >> 4;

    const int q0 = chunk * 64 + wave * 16;    // wave owns rows q0..q0+15
    const size_t base = (size_t)head * (S_LEN * D_DIM);
    const float qscale = 0.125f * 1.44269504088896340736f;   // D^-0.5 * log2(e)

    __shared__ __align__(16) __bf16 Klds[2][64][64];   // [buf][key][d], col ^ ((key&7)<<3)
    __shared__ __align__(16) __bf16 Vt[2][64][64];     // [buf][d][key], col ^ ((d&7)<<3)
    __shared__ __align__(16) __bf16 Plds[4][16][64];   // per wave [q][key], col ^ ((q&7)<<3)

    // staging coords
    const int rk = tid >> 2;            // K row 0..63
    const int ck = (tid & 3) << 4;      // K col 0,16,32,48
    const int kp = tid & 31;            // V key-pair (keys 2kp, 2kp+1)
    const int dc = tid >> 5;            // V d-chunk 0..7
    const int swk = (rk & 7) << 3;

    // ---- Q fragments (A-frag: row=l15, k=lhi*8+e), 2 k-halves ----
    bf16x8 qf[2];
    {
        const float* qrow = Q + base + (size_t)(q0 + l15) * D_DIM + lhi * 8;
        #pragma unroll
        for (int h = 0; h < 2; ++h) {
            f32x4 a = *(const f32x4*)(qrow + h * 32);
            f32x4 bq = *(const f32x4*)(qrow + h * 32 + 4);
            bf16x8 t;
            #pragma unroll
            for (int e = 0; e < 4; ++e) { t[e] = (__bf16)(a[e] * qscale); t[e + 4] = (__bf16)(bq[e] * qscale); }
            qf[h] = t;
        }
    }

    f32x4 acc[4];
    #pragma unroll
    for (int td = 0; td < 4; ++td) acc[td] = (f32x4){0.f, 0.f, 0.f, 0.f};
    float m_r[4], l_r[4];
    #pragma unroll
    for (int r = 0; r < 4; ++r) { m_r[r] = -1e30f; l_r[r] = 0.f; }

    f32x4 pk[4], pva[2], pvb[2];

    // ---- prologue: stage tile 0 into buf 0 ----
    {
        const float* ks = K + base + (size_t)rk * D_DIM + ck;
        #pragma unroll
        for (int i = 0; i < 4; ++i) pk[i] = *(const f32x4*)(ks + 4 * i);
        const float* v0 = V + base + (size_t)(2 * kp) * D_DIM + dc * 8;
        pva[0] = *(const f32x4*)v0;           pva[1] = *(const f32x4*)(v0 + 4);
        pvb[0] = *(const f32x4*)(v0 + D_DIM); pvb[1] = *(const f32x4*)(v0 + D_DIM + 4);
        bf16x8 k0, k1;
        #pragma unroll
        for (int e = 0; e < 4; ++e) {
            k0[e] = (__bf16)pk[0][e]; k0[e + 4] = (__bf16)pk[1][e];
            k1[e] = (__bf16)pk[2][e]; k1[e + 4] = (__bf16)pk[3][e];
        }
        *(bf16x8*)&Klds[0][rk][ck ^ swk] = k0;
        *(bf16x8*)&Klds[0][rk][(ck + 8) ^ swk] = k1;
        #pragma unroll
        for (int jj = 0; jj < 8; ++jj) {
            const int d = dc * 8 + jj;
            const float av = (jj < 4) ? pva[0][jj & 3] : pva[1][jj & 3];
            const float bv = (jj < 4) ? pvb[0][jj & 3] : pvb[1][jj & 3];
            union { __bf16 h[2]; unsigned int u; } t;
            t.h[0] = (__bf16)av; t.h[1] = (__bf16)bv;
            *(unsigned int*)&Vt[0][d][(2 * kp) ^ ((d & 7) << 3)] = t.u;
        }
    }

    const int nt = chunk + 1;
    for (int kt = 0; kt < nt; ++kt) {
        const int cur = kt & 1;
        __syncthreads();                 // buf[cur] staged; prior reads of buf[cur^1] done

        const bool pre = (kt + 1 < nt);
        if (pre) {                       // issue next-tile loads; latency hides under compute
            const int kv1 = (kt + 1) << 6;
            const float* ks = K + base + (size_t)(kv1 + rk) * D_DIM + ck;
            #pragma unroll
            for (int i = 0; i < 4; ++i) pk[i] = *(const f32x4*)(ks + 4 * i);
            const float* v0 = V + base + (size_t)(kv1 + 2 * kp) * D_DIM + dc * 8;
            pva[0] = *(const f32x4*)v0;           pva[1] = *(const f32x4*)(v0 + 4);
            pvb[0] = *(const f32x4*)(v0 + D_DIM); pvb[1] = *(const f32x4*)(v0 + D_DIM + 4);
        }

        // ---- S = Q K^T : 4 col-tiles x 2 k-halves ----
        f32x4 s[4];
        #pragma unroll
        for (int ct = 0; ct < 4; ++ct) s[ct] = (f32x4){0.f, 0.f, 0.f, 0.f};
        __builtin_amdgcn_s_setprio(1);
        #pragma unroll
        for (int h = 0; h < 2; ++h) {
            #pragma unroll
            for (int ct = 0; ct < 4; ++ct) {
                const int krow = ct * 16 + l15;
                bf16x8 kf = *(const bf16x8*)&Klds[cur][krow][(h * 32 + lhi * 8) ^ ((l15 & 7) << 3)];
                s[ct] = __builtin_amdgcn_mfma_f32_16x16x32_bf16(qf[h], kf, s[ct], 0, 0, 0);
            }
        }
        __builtin_amdgcn_s_setprio(0);

        // ---- causal mask: only the last tile straddles the diagonal ----
        if (kt == nt - 1) {
            const int kv0 = kt << 6;
            #pragma unroll
            for (int ct = 0; ct < 4; ++ct)
                #pragma unroll
                for (int r = 0; r < 4; ++r) {
                    const int kg = kv0 + ct * 16 + l15;
                    const int qg = q0 + lhi * 4 + r;
                    if (kg > qg) s[ct][r] = -1e30f;
                }
        }

        // ---- online softmax with defer-max (T13, log2 domain, THR=8 -> P<=256) ----
        float tm[4];
        #pragma unroll
        for (int r = 0; r < 4; ++r) {
            float mm = fmaxf(fmaxf(s[0][r], s[1][r]), fmaxf(s[2][r], s[3][r]));
            mm = fmaxf(mm, __shfl_xor(mm, 1));
            mm = fmaxf(mm, __shfl_xor(mm, 2));
            mm = fmaxf(mm, __shfl_xor(mm, 4));
            mm = fmaxf(mm, __shfl_xor(mm, 8));
            tm[r] = mm;
        }
        float need = fmaxf(fmaxf(tm[0] - m_r[0], tm[1] - m_r[1]),
                           fmaxf(tm[2] - m_r[2], tm[3] - m_r[3]));
        if (!__all(need <= 8.0f)) {
            #pragma unroll
            for (int r = 0; r < 4; ++r) {
                const float mn = fmaxf(m_r[r], tm[r]);
                const float f = exp2f(m_r[r] - mn);
                m_r[r] = mn;
                l_r[r] *= f;
                #pragma unroll
                for (int td = 0; td < 4; ++td) acc[td][r] *= f;
            }
        }
        #pragma unroll
        for (int r = 0; r < 4; ++r) {
            float p0 = exp2f(s[0][r] - m_r[r]);
            float p1 = exp2f(s[1][r] - m_r[r]);
            float p2 = exp2f(s[2][r] - m_r[r]);
            float p3 = exp2f(s[3][r] - m_r[r]);
            s[0][r] = p0; s[1][r] = p1; s[2][r] = p2; s[3][r] = p3;
            float ps = (p0 + p1) + (p2 + p3);
            ps += __shfl_xor(ps, 1);
            ps += __shfl_xor(ps, 2);
            ps += __shfl_xor(ps, 4);
            ps += __shfl_xor(ps, 8);
            l_r[r] += ps;
        }

        // ---- P (C/D layout) -> per-wave LDS (swizzled) -> A-frags ----
        #pragma unroll
        for (int ct = 0; ct < 4; ++ct)
            #pragma unroll
            for (int r = 0; r < 4; ++r) {
                const int prow = lhi * 4 + r;
                Plds[wave][prow][(ct * 16 + l15) ^ ((prow & 7) << 3)] = (__bf16)s[ct][r];
            }
        asm volatile("s_waitcnt lgkmcnt(0)" ::: "memory");
        bf16x8 pf[2];
        #pragma unroll
        for (int kh = 0; kh < 2; ++kh)
            pf[kh] = *(const bf16x8*)&Plds[wave][l15][(kh * 32 + lhi * 8) ^ ((l15 & 7) << 3)];
        asm volatile("" ::: "memory");

        // ---- O += P V ----
        __builtin_amdgcn_s_setprio(1);
        #pragma unroll
        for (int kh = 0; kh < 2; ++kh) {
            #pragma unroll
            for (int td = 0; td < 4; ++td) {
                const int vrow = td * 16 + l15;
                bf16x8 vf = *(const bf16x8*)&Vt[cur][vrow][(kh * 32 + lhi * 8) ^ ((vrow & 7) << 3)];
                acc[td] = __builtin_amdgcn_mfma_f32_16x16x32_bf16(pf[kh], vf, acc[td], 0, 0, 0);
            }
        }
        __builtin_amdgcn_s_setprio(0);

        if (pre) {                       // cvt + write into idle buffer (no barrier needed)
            const int nxt = cur ^ 1;
            bf16x8 k0, k1;
            #pragma unroll
            for (int e = 0; e < 4; ++e) {
                k0[e] = (__bf16)pk[0][e]; k0[e + 4] = (__bf16)pk[1][e];
                k1[e] = (__bf16)pk[2][e]; k1[e + 4] = (__bf16)pk[3][e];
            }
            *(bf16x8*)&Klds[nxt][rk][ck ^ swk] = k0;
            *(bf16x8*)&Klds[nxt][rk][(ck + 8) ^ swk] = k1;
            #pragma unroll
            for (int jj = 0; jj < 8; ++jj) {
                const int d = dc * 8 + jj;
                const float av = (jj < 4) ? pva[0][jj & 3] : pva[1][jj & 3];
                const float bv = (jj < 4) ? pvb[0][jj & 3] : pvb[1][jj & 3];
                union { __bf16 h[2]; unsigned int u; } t;
                t.h[0] = (__bf16)av; t.h[1] = (__bf16)bv;
                *(unsigned int*)&Vt[nxt][d][(2 * kp) ^ ((d & 7) << 3)] = t.u;
            }
        }
    }

    // ---- epilogue ----
    float* orow = O + base + (size_t)q0 * D_DIM;
    #pragma unroll
    for (int r = 0; r < 4; ++r) {
        const float inv = 1.0f / l_r[r];
        #pragma unroll
        for (int td = 0; td < 4; ++td)
            orow[(size_t)(lhi * 4 + r) * D_DIM + td * 16 + l15] = acc[td][r] * inv;
    }
}

extern "C" void kernel_launch(void* const* d_in, const int* in_sizes, int n_in,
                              void* d_out, int out_size, void* d_ws, size_t ws_size,
                              hipStream_t stream) {
    const float* q = (const float*)d_in[0];
    const float* k = (const float*)d_in[1];
    const float* v = (const float*)d_in[2];
    float* o = (float*)d_out;
    attn_fwd<<<dim3(1024), dim3(256), 0, stream>>>(q, k, v, o);
}

// Round 5
// 58.465 us; speedup vs baseline: 5.0647x; 1.5371x over previous
//
#include <hip/hip_runtime.h>

typedef __bf16 bf16x8 __attribute__((ext_vector_type(8)));
typedef float f32x4 __attribute__((ext_vector_type(4)));

#define S_LEN 2048
#define D_DIM 64

__global__ __launch_bounds__(256, 4) void attn_fwd(const float* __restrict__ Q,
                                                   const float* __restrict__ K,
                                                   const float* __restrict__ V,
                                                   float* __restrict__ O) {
    // Deterministic CU-pairing + XCD-locality mapping (1024 blocks, 4/CU).
    const int b    = blockIdx.x;
    const int xcd  = b & 7;
    const int cs   = (b >> 3) & 31;
    const int j    = b >> 8;                  // 0..3
    const int head = xcd * 4 + (cs >> 3);     // 4 heads per XCD
    const int slot = cs & 7;
    const int chunk = (j == 0) ? slot : (j == 1) ? (31 - slot)
                    : (j == 2) ? (slot + 8) : (23 - slot);   // 64-row q-chunk, 0..31

    const int tid  = threadIdx.x;
    const int wave = tid >> 6;
    const int lane = tid & 63;
    const int l15  = lane & 15;
    const int lhi  = lane >> 4;

    const int q0 = chunk * 64 + wave * 16;    // wave owns rows q0..q0+15
    const size_t base = (size_t)head * (S_LEN * D_DIM);
    const float qscale = 0.125f * 1.44269504088896340736f;   // D^-0.5 * log2(e)

    __shared__ __align__(16) __bf16 Klds[2][64][64];   // [buf][key][d], col ^ ((key&7)<<3)
    __shared__ __align__(16) __bf16 Vt[2][64][64];     // [buf][d][key], col ^ ((d&7)<<3)
    __shared__ __align__(16) __bf16 Plds[4][16][64];   // per wave [q][key], col ^ ((q&7)<<3)

    // staging coords
    const int rk = tid >> 2;            // K row 0..63
    const int ck = (tid & 3) << 4;      // K col 0,16,32,48
    const int kp = tid & 31;            // V key-pair (keys 2kp, 2kp+1)
    const int dc = tid >> 5;            // V d-chunk 0..7
    const int swk = (rk & 7) << 3;

    // ---- Q fragments (B-frag for swapped QK^T: col=l15, k=lhi*8+e) ----
    bf16x8 qf[2];
    {
        const float* qrow = Q + base + (size_t)(q0 + l15) * D_DIM + lhi * 8;
        #pragma unroll
        for (int h = 0; h < 2; ++h) {
            f32x4 a = *(const f32x4*)(qrow + h * 32);
            f32x4 bq = *(const f32x4*)(qrow + h * 32 + 4);
            bf16x8 t;
            #pragma unroll
            for (int e = 0; e < 4; ++e) { t[e] = (__bf16)(a[e] * qscale); t[e + 4] = (__bf16)(bq[e] * qscale); }
            qf[h] = t;
        }
    }

    f32x4 acc[4];
    #pragma unroll
    for (int td = 0; td < 4; ++td) acc[td] = (f32x4){0.f, 0.f, 0.f, 0.f};
    float m_r = -1e30f, l_r = 0.f;      // per-lane: q-row = q0 + l15

    f32x4 pk[4], pva[2], pvb[2];

    // ---- prologue: stage tile 0 into buf 0 ----
    {
        const float* ks = K + base + (size_t)rk * D_DIM + ck;
        #pragma unroll
        for (int i = 0; i < 4; ++i) pk[i] = *(const f32x4*)(ks + 4 * i);
        const float* v0 = V + base + (size_t)(2 * kp) * D_DIM + dc * 8;
        pva[0] = *(const f32x4*)v0;           pva[1] = *(const f32x4*)(v0 + 4);
        pvb[0] = *(const f32x4*)(v0 + D_DIM); pvb[1] = *(const f32x4*)(v0 + D_DIM + 4);
        bf16x8 k0, k1;
        #pragma unroll
        for (int e = 0; e < 4; ++e) {
            k0[e] = (__bf16)pk[0][e]; k0[e + 4] = (__bf16)pk[1][e];
            k1[e] = (__bf16)pk[2][e]; k1[e + 4] = (__bf16)pk[3][e];
        }
        *(bf16x8*)&Klds[0][rk][ck ^ swk] = k0;
        *(bf16x8*)&Klds[0][rk][(ck + 8) ^ swk] = k1;
        #pragma unroll
        for (int jj = 0; jj < 8; ++jj) {
            const int d = dc * 8 + jj;
            const float av = (jj < 4) ? pva[0][jj & 3] : pva[1][jj & 3];
            const float bv = (jj < 4) ? pvb[0][jj & 3] : pvb[1][jj & 3];
            union { __bf16 h[2]; unsigned int u; } t;
            t.h[0] = (__bf16)av; t.h[1] = (__bf16)bv;
            *(unsigned int*)&Vt[0][d][(2 * kp) ^ ((d & 7) << 3)] = t.u;
        }
    }

    const int nt = chunk + 1;
    for (int kt = 0; kt < nt; ++kt) {
        const int cur = kt & 1;
        __syncthreads();                 // buf[cur] staged; prior reads of buf[cur^1] done

        const bool pre = (kt + 1 < nt);
        if (pre) {                       // issue next-tile loads; latency hides under compute
            const int kv1 = (kt + 1) << 6;
            const float* ks = K + base + (size_t)(kv1 + rk) * D_DIM + ck;
            #pragma unroll
            for (int i = 0; i < 4; ++i) pk[i] = *(const f32x4*)(ks + 4 * i);
            const float* v0 = V + base + (size_t)(kv1 + 2 * kp) * D_DIM + dc * 8;
            pva[0] = *(const f32x4*)v0;           pva[1] = *(const f32x4*)(v0 + 4);
            pvb[0] = *(const f32x4*)(v0 + D_DIM); pvb[1] = *(const f32x4*)(v0 + D_DIM + 4);
        }

        // ---- S^T = K Q^T : swapped operands, same fragments.
        //      C/D: col = q = l15, row = k = kv0 + ct*16 + lhi*4 + r ----
        f32x4 s[4];
        #pragma unroll
        for (int ct = 0; ct < 4; ++ct) s[ct] = (f32x4){0.f, 0.f, 0.f, 0.f};
        __builtin_amdgcn_s_setprio(1);
        #pragma unroll
        for (int h = 0; h < 2; ++h) {
            #pragma unroll
            for (int ct = 0; ct < 4; ++ct) {
                const int krow = ct * 16 + l15;
                bf16x8 kf = *(const bf16x8*)&Klds[cur][krow][(h * 32 + lhi * 8) ^ ((l15 & 7) << 3)];
                s[ct] = __builtin_amdgcn_mfma_f32_16x16x32_bf16(kf, qf[h], s[ct], 0, 0, 0);
            }
        }
        __builtin_amdgcn_s_setprio(0);

        // ---- causal mask: only the last tile straddles the diagonal ----
        if (kt == nt - 1) {
            const int kv0 = kt << 6;
            const int qg = q0 + l15;
            #pragma unroll
            for (int ct = 0; ct < 4; ++ct)
                #pragma unroll
                for (int r = 0; r < 4; ++r) {
                    const int kg = kv0 + ct * 16 + lhi * 4 + r;
                    if (kg > qg) s[ct][r] = -1e30f;
                }
        }

        // ---- in-register online softmax (lane owns one q-row's 16 scores) ----
        float mm = fmaxf(fmaxf(fmaxf(s[0][0], s[0][1]), fmaxf(s[0][2], s[0][3])),
                         fmaxf(fmaxf(s[1][0], s[1][1]), fmaxf(s[1][2], s[1][3])));
        mm = fmaxf(mm, fmaxf(fmaxf(fmaxf(s[2][0], s[2][1]), fmaxf(s[2][2], s[2][3])),
                             fmaxf(fmaxf(s[3][0], s[3][1]), fmaxf(s[3][2], s[3][3]))));
        mm = fmaxf(mm, __shfl_xor(mm, 16));
        mm = fmaxf(mm, __shfl_xor(mm, 32));
        if (!__all(mm - m_r <= 8.0f)) {          // defer-max (T13): rescale rarely
            const float mn = fmaxf(m_r, mm);
            const float f = exp2f(m_r - mn);
            m_r = mn;
            l_r *= f;
            #pragma unroll
            for (int r = 0; r < 4; ++r) {
                const float fr = __shfl(f, lhi * 4 + r);   // factor for acc row q=lhi*4+r
                #pragma unroll
                for (int td = 0; td < 4; ++td) acc[td][r] *= fr;
            }
        }
        float ps = 0.f;
        #pragma unroll
        for (int ct = 0; ct < 4; ++ct)
            #pragma unroll
            for (int r = 0; r < 4; ++r) {
                const float p = exp2f(s[ct][r] - m_r);
                s[ct][r] = p;
                ps += p;
            }
        ps += __shfl_xor(ps, 16);
        ps += __shfl_xor(ps, 32);
        l_r += ps;

        // ---- P (S^T layout) -> per-wave LDS (swizzled b64 writes) -> A-frags ----
        #pragma unroll
        for (int ct = 0; ct < 4; ++ct) {
            union { __bf16 h[4]; unsigned long long u; } pw;
            #pragma unroll
            for (int r = 0; r < 4; ++r) pw.h[r] = (__bf16)s[ct][r];
            *(unsigned long long*)&Plds[wave][l15][(ct * 16 + lhi * 4) ^ ((l15 & 7) << 3)] = pw.u;
        }
        asm volatile("s_waitcnt lgkmcnt(0)" ::: "memory");
        bf16x8 pf[2];
        #pragma unroll
        for (int kh = 0; kh < 2; ++kh)
            pf[kh] = *(const bf16x8*)&Plds[wave][l15][(kh * 32 + lhi * 8) ^ ((l15 & 7) << 3)];
        asm volatile("" ::: "memory");

        // ---- O += P V ----
        __builtin_amdgcn_s_setprio(1);
        #pragma unroll
        for (int kh = 0; kh < 2; ++kh) {
            #pragma unroll
            for (int td = 0; td < 4; ++td) {
                const int vrow = td * 16 + l15;
                bf16x8 vf = *(const bf16x8*)&Vt[cur][vrow][(kh * 32 + lhi * 8) ^ ((vrow & 7) << 3)];
                acc[td] = __builtin_amdgcn_mfma_f32_16x16x32_bf16(pf[kh], vf, acc[td], 0, 0, 0);
            }
        }
        __builtin_amdgcn_s_setprio(0);

        if (pre) {                       // cvt + write into idle buffer (no barrier needed)
            const int nxt = cur ^ 1;
            bf16x8 k0, k1;
            #pragma unroll
            for (int e = 0; e < 4; ++e) {
                k0[e] = (__bf16)pk[0][e]; k0[e + 4] = (__bf16)pk[1][e];
                k1[e] = (__bf16)pk[2][e]; k1[e + 4] = (__bf16)pk[3][e];
            }
            *(bf16x8*)&Klds[nxt][rk][ck ^ swk] = k0;
            *(bf16x8*)&Klds[nxt][rk][(ck + 8) ^ swk] = k1;
            #pragma unroll
            for (int jj = 0; jj < 8; ++jj) {
                const int d = dc * 8 + jj;
                const float av = (jj < 4) ? pva[0][jj & 3] : pva[1][jj & 3];
                const float bv = (jj < 4) ? pvb[0][jj & 3] : pvb[1][jj & 3];
                union { __bf16 h[2]; unsigned int u; } t;
                t.h[0] = (__bf16)av; t.h[1] = (__bf16)bv;
                *(unsigned int*)&Vt[nxt][d][(2 * kp) ^ ((d & 7) << 3)] = t.u;
            }
        }
    }

    // ---- epilogue: O = acc / l  (l for row q=lhi*4+r lives on lane lhi*4+r) ----
    float* orow = O + base + (size_t)q0 * D_DIM;
    #pragma unroll
    for (int r = 0; r < 4; ++r) {
        const float inv = 1.0f / __shfl(l_r, lhi * 4 + r);
        #pragma unroll
        for (int td = 0; td < 4; ++td)
            orow[(size_t)(lhi * 4 + r) * D_DIM + td * 16 + l15] = acc[td][r] * inv;
    }
}

extern "C" void kernel_launch(void* const* d_in, const int* in_sizes, int n_in,
                              void* d_out, int out_size, void* d_ws, size_t ws_size,
                              hipStream_t stream) {
    const float* q = (const float*)d_in[0];
    const float* k = (const float*)d_in[1];
    const float* v = (const float*)d_in[2];
    float* o = (float*)d_out;
    attn_fwd<<<dim3(1024), dim3(256), 0, stream>>>(q, k, v, o);
}